// Round 2
// baseline (309.677 us; speedup 1.0000x reference)
//
#include <hip/hip_runtime.h>
#include <hip/hip_bf16.h>

typedef unsigned short u16;
typedef __attribute__((ext_vector_type(8))) short bf16x8;  // 8 bf16 = 4 VGPRs
typedef __attribute__((ext_vector_type(4))) float f32x4;

#define NH   32
#define HD   128
#define SEQ  2048
#define BQ   64
#define BK   64
#define KSTR 136   // Q/K LDS row stride (elems): 128+8 pad -> 2-way bank aliasing (free)
#define PSTR 72    // P LDS row stride

// Vt swizzle: phys = d*64 + (((j>>3) ^ (d&7) ^ ((d>>3)&7))<<3) + (j&7)
__device__ __forceinline__ int vt_key(int d) { return (d & 7) ^ ((d >> 3) & 7); }

__device__ __forceinline__ u16 f2b(float x) {
  __hip_bfloat16 hb = __float2bfloat16(x);
  return *(u16*)&hb;
}

// load 8 fp32 from src (32B), convert to bf16, store 16B to LDS dst
__device__ __forceinline__ void cvt_store8(u16* dst, const float* src) {
  float4 a = *(const float4*)(src);
  float4 b = *(const float4*)(src + 4);
  u16 t[8];
  t[0] = f2b(a.x); t[1] = f2b(a.y); t[2] = f2b(a.z); t[3] = f2b(a.w);
  t[4] = f2b(b.x); t[5] = f2b(b.y); t[6] = f2b(b.z); t[7] = f2b(b.w);
  *(uint4*)dst = *(uint4*)t;
}

__global__ __launch_bounds__(256, 2)
void attn_roco(const float* __restrict__ Qg, const float* __restrict__ Kg,
               const float* __restrict__ Vg, float* __restrict__ Og,
               float* __restrict__ ws) {
  __shared__ __align__(16) u16 Qs[BQ * KSTR];
  __shared__ __align__(16) u16 Ks[BK * KSTR];
  __shared__ __align__(16) u16 Vt[HD * BK];       // transposed + XOR-swizzled
  __shared__ __align__(16) u16 Ps[4 * 16 * PSTR]; // per-wave P tiles

  const int tid = threadIdx.x;
  const int wv  = tid >> 6;
  const int ln  = tid & 63;
  const int qd  = ln >> 4;   // quad
  const int cc  = ln & 15;

  const int h  = (int)blockIdx.x & 31;
  const int qt = 31 - (int)(blockIdx.x >> 5);   // heavy (long-KV) tiles first
  const int qbase  = qt * BQ;
  const int ntiles = qt + 1;

  // ---- stage Q tile (once), fp32 -> bf16 ----
  #pragma unroll
  for (int it = 0; it < 4; ++it) {
    int c = tid + it * 256;
    int row = c >> 4, col = (c & 15) << 3;
    cvt_store8(Qs + row * KSTR + col,
               Qg + ((size_t)(qbase + row) * NH + h) * HD + col);
  }

  const float beta = 0.08838834764831845f * 1.4426950408889634f; // 1/sqrt(128)*log2(e)
  const int rbase = wv * 16 + qd * 4;

  float m[4], ls[4];
  #pragma unroll
  for (int r = 0; r < 4; ++r) { m[r] = -1e30f; ls[r] = 0.f; }

  // ================= PASS A: row max + sumexp =================
  for (int t = 0; t < ntiles; ++t) {
    __syncthreads();
    #pragma unroll
    for (int it = 0; it < 4; ++it) {
      int c = tid + it * 256;
      int row = c >> 4, col = (c & 15) << 3;
      cvt_store8(Ks + row * KSTR + col,
                 Kg + ((size_t)(t * BK + row) * NH + h) * HD + col);
    }
    __syncthreads();

    f32x4 S[4];
    #pragma unroll
    for (int f = 0; f < 4; ++f)
      #pragma unroll
      for (int r = 0; r < 4; ++r) S[f][r] = 0.f;

    #pragma unroll
    for (int kd = 0; kd < 4; ++kd) {
      bf16x8 a = *(const bf16x8*)(Qs + (wv * 16 + cc) * KSTR + kd * 32 + qd * 8);
      #pragma unroll
      for (int f = 0; f < 4; ++f) {
        bf16x8 b = *(const bf16x8*)(Ks + (f * 16 + cc) * KSTR + kd * 32 + qd * 8);
        S[f] = __builtin_amdgcn_mfma_f32_16x16x32_bf16(a, b, S[f], 0, 0, 0);
      }
    }

    const bool diag = (t == qt);
    #pragma unroll
    for (int r = 0; r < 4; ++r) {
      const int iloc = rbase + r;
      float tv[4], tmax = -1e30f;
      #pragma unroll
      for (int f = 0; f < 4; ++f) {
        float s = S[f][r] * beta;
        if (diag && (f * 16 + cc) > iloc) s = -1e30f;
        tv[f] = s;
        tmax = fmaxf(tmax, s);
      }
      #pragma unroll
      for (int off = 1; off < 16; off <<= 1)
        tmax = fmaxf(tmax, __shfl_xor(tmax, off));
      const float mn = fmaxf(m[r], tmax);
      float sm = 0.f;
      #pragma unroll
      for (int f = 0; f < 4; ++f) sm += exp2f(tv[f] - mn);
      #pragma unroll
      for (int off = 1; off < 16; off <<= 1)
        sm += __shfl_xor(sm, off);
      ls[r] = ls[r] * exp2f(m[r] - mn) + sm;
      m[r] = mn;
    }
  }

  float invl[4];
  #pragma unroll
  for (int r = 0; r < 4; ++r) invl[r] = 1.f / ls[r];

  f32x4 O[8];
  #pragma unroll
  for (int f = 0; f < 8; ++f)
    #pragma unroll
    for (int r = 0; r < 4; ++r) O[f][r] = 0.f;

  float* ws_s = ws + (size_t)h * SEQ;
  float* ws_q = ws + (size_t)NH * SEQ + (size_t)h * SEQ;

  // ================= PASS B: exact P, O += P*V, column sums =================
  for (int t = 0; t < ntiles; ++t) {
    __syncthreads();
    #pragma unroll
    for (int it = 0; it < 4; ++it) {
      int c = tid + it * 256;
      int row = c >> 4, col = (c & 15) << 3;
      cvt_store8(Ks + row * KSTR + col,
                 Kg + ((size_t)(t * BK + row) * NH + h) * HD + col);
    }
    #pragma unroll
    for (int it = 0; it < 4; ++it) {
      int c = tid + it * 256;
      int j = c >> 4, d0 = (c & 15) << 3;
      const float* vp = Vg + ((size_t)(t * BK + j) * NH + h) * HD + d0;
      float4 va = *(const float4*)(vp);
      float4 vb = *(const float4*)(vp + 4);
      float v8[8] = {va.x, va.y, va.z, va.w, vb.x, vb.y, vb.z, vb.w};
      #pragma unroll
      for (int e = 0; e < 8; ++e) {
        int d = d0 + e;
        Vt[d * BK + ((((j >> 3) ^ vt_key(d)) << 3)) + (j & 7)] = f2b(v8[e]);
      }
    }
    __syncthreads();

    f32x4 S[4];
    #pragma unroll
    for (int f = 0; f < 4; ++f)
      #pragma unroll
      for (int r = 0; r < 4; ++r) S[f][r] = 0.f;

    #pragma unroll
    for (int kd = 0; kd < 4; ++kd) {
      bf16x8 a = *(const bf16x8*)(Qs + (wv * 16 + cc) * KSTR + kd * 32 + qd * 8);
      #pragma unroll
      for (int f = 0; f < 4; ++f) {
        bf16x8 b = *(const bf16x8*)(Ks + (f * 16 + cc) * KSTR + kd * 32 + qd * 8);
        S[f] = __builtin_amdgcn_mfma_f32_16x16x32_bf16(a, b, S[f], 0, 0, 0);
      }
    }

    const bool diag = (t == qt);
    float cs[4] = {0.f, 0.f, 0.f, 0.f}, cq[4] = {0.f, 0.f, 0.f, 0.f};
    #pragma unroll
    for (int r = 0; r < 4; ++r) {
      const int iloc = rbase + r;
      #pragma unroll
      for (int f = 0; f < 4; ++f) {
        float s = S[f][r] * beta;
        if (diag && (f * 16 + cc) > iloc) s = -1e30f;
        float p = exp2f(s - m[r]) * invl[r];   // final prob, <= 1
        cs[f] += p;
        cq[f] += p * p;
        Ps[(wv * 16 + qd * 4 + r) * PSTR + f * 16 + cc] = f2b(p);
      }
    }
    // column sums across the wave's 16 rows: combine quads, then one atomic/column
    #pragma unroll
    for (int f = 0; f < 4; ++f) {
      cs[f] += __shfl_xor(cs[f], 16); cs[f] += __shfl_xor(cs[f], 32);
      cq[f] += __shfl_xor(cq[f], 16); cq[f] += __shfl_xor(cq[f], 32);
      if (qd == f) {
        int j = t * BK + f * 16 + cc;
        atomicAdd(ws_s + j, cs[f]);
        atomicAdd(ws_q + j, cq[f]);
      }
    }
    // PV: O[16 x 128] += P[16 x 64] * V[64 x 128]
    #pragma unroll
    for (int ks = 0; ks < 2; ++ks) {
      bf16x8 a = *(const bf16x8*)(Ps + (wv * 16 + cc) * PSTR + ks * 32 + qd * 8);
      #pragma unroll
      for (int f2 = 0; f2 < 8; ++f2) {
        int d = f2 * 16 + cc;
        int jb = ks * 4 + qd;   // (ks*32 + qd*8) >> 3
        bf16x8 b = *(const bf16x8*)(Vt + d * BK + ((jb ^ vt_key(d)) << 3));
        O[f2] = __builtin_amdgcn_mfma_f32_16x16x32_bf16(a, b, O[f2], 0, 0, 0);
      }
    }
  }

  // ---- epilogue: O already normalized (invl folded into P), fp32 out ----
  #pragma unroll
  for (int f2 = 0; f2 < 8; ++f2) {
    #pragma unroll
    for (int r = 0; r < 4; ++r) {
      int i = qbase + rbase + r;
      int d = f2 * 16 + cc;
      Og[((size_t)i * NH + h) * HD + d] = O[f2][r];
    }
  }
}

__global__ void roco_fin(const float* __restrict__ ws, float* __restrict__ out) {
  int i = (int)blockIdx.x * 256 + (int)threadIdx.x;  // 2*NH*SEQ = 131072 total
  out[i] = ws[i];
}

extern "C" void kernel_launch(void* const* d_in, const int* in_sizes, int n_in,
                              void* d_out, int out_size, void* d_ws, size_t ws_size,
                              hipStream_t stream) {
  (void)in_sizes; (void)n_in; (void)out_size; (void)ws_size;
  const float* Qg = (const float*)d_in[0];
  const float* Kg = (const float*)d_in[1];
  const float* Vg = (const float*)d_in[2];
  float* Og = (float*)d_out;
  float* ws = (float*)d_ws;

  // zero the fp32 roco accumulators (graph-capture-safe async memset)
  hipMemsetAsync(d_ws, 0, (size_t)2 * NH * SEQ * sizeof(float), stream);

  attn_roco<<<dim3(NH * (SEQ / BQ)), dim3(256), 0, stream>>>(Qg, Kg, Vg, Og, ws);

  // copy fp32 accumulators -> fp32 outputs (roco_score then roco_sq, contiguous)
  roco_fin<<<dim3((2 * NH * SEQ) / 256), dim3(256), 0, stream>>>(
      ws, Og + (size_t)SEQ * NH * HD);
}